// Round 4
// baseline (2667.735 us; speedup 1.0000x reference)
//
#include <hip/hip_runtime.h>
#include <hip/hip_bf16.h>
#include <stdint.h>

// Encoder: X->(transpose)->QKV GEMMs -> attention(softmax) -> Wx GEMM -> 128-step LSTM
// B=512 T=128 N=256 H=256, all inputs f32, output f32 (B,T,H).
// Round 4: k_lstm3 — zero W-register-residency. All of W_hh streamed per step
// L2 -> LDS (global_load_lds, 2x64KB dbuf, 8 pieces/step). Arch-VGPR demand ~70
// by construction (rounds 1-3 died to the allocator's 128-VGPR cap + spill).

#define DI __device__ __forceinline__

typedef __attribute__((ext_vector_type(8))) short bf16x8;   // 8 bf16 = 4 VGPR (MFMA A/B frag)
typedef __attribute__((ext_vector_type(4))) short short4v;  // 8B
typedef __attribute__((ext_vector_type(4))) float f32x4;    // MFMA C/D frag
typedef __attribute__((ext_vector_type(4))) int int4v;      // 16B

union U8 { bf16x8 v; short4v h[2]; int4v i; };

DI unsigned short f2bf(float x){
  union { float f; unsigned u; } v; v.f = x;
  unsigned r = v.u + 0x7fffu + ((v.u >> 16) & 1u);
  return (unsigned short)(r >> 16);
}
DI float bf2f(unsigned short x){
  union { unsigned u; float f; } v; v.u = ((unsigned)x) << 16; return v.f;
}
DI float rcp_(float x){ return __builtin_amdgcn_rcpf(x); }
DI float sigm(float x){ return rcp_(1.0f + __expf(-x)); }
DI float tanhf_(float x){ return 1.0f - 2.0f * rcp_(1.0f + __expf(2.0f * x)); }

DI void g2l16(const void* g, void* l){
  __builtin_amdgcn_global_load_lds(
      (const __attribute__((address_space(1))) unsigned int*)g,
      (__attribute__((address_space(3))) unsigned int*)l, 16, 0, 0);
}

#define BB 512
#define TT 128
#define NN 256
#define HH 256

// ---------------------------------------------------------------------------
// K0: cast weights to bf16, fuse biases
__global__ void k_prep(const float* __restrict__ Wq, const float* __restrict__ Wk,
                       const float* __restrict__ Wv, const float* __restrict__ Wih,
                       const float* __restrict__ bih, const float* __restrict__ bhh,
                       unsigned short* __restrict__ wqb, unsigned short* __restrict__ wkb,
                       unsigned short* __restrict__ wvb, unsigned short* __restrict__ wihb,
                       float* __restrict__ bias){
  int i = blockIdx.x * 256 + threadIdx.x;
  if (i < 16384){ wqb[i] = f2bf(Wq[i]); wkb[i] = f2bf(Wk[i]); wvb[i] = f2bf(Wv[i]); }
  if (i < 262144){ wihb[i] = f2bf(Wih[i]); }
  if (i < 1024){ bias[i] = bih[i] + bhh[i]; }
}

// K0b: W_hh -> fragment-major bf16, PRE-SWIZZLED for bank-conflict-free LDS reads.
// Frag (j, c=kk*4+g) holds W[j][kk*32+4g+{0..3}] , W[j][kk*32+16+4g+{0..3}];
// stored at byte j*512 + ((c ^ (j&7)) << 4).  (global_load_lds writes LDS linearly,
// so the swizzle must be baked into the global source — G21.)
__global__ void k_prep2(const float* __restrict__ Whh, unsigned short* __restrict__ whh_f){
  int idx = blockIdx.x * 256 + threadIdx.x;   // 8192 = 1024 j x 8 kk
  int j = idx >> 3, kk = idx & 7;
  const float* src = Whh + j * 256 + kk * 32;
  unsigned short o[32];
  #pragma unroll
  for (int g = 0; g < 4; ++g)
    #pragma unroll
    for (int e = 0; e < 4; ++e){
      o[g * 8 + e]     = f2bf(src[4 * g + e]);
      o[g * 8 + 4 + e] = f2bf(src[16 + 4 * g + e]);
    }
  char* base = (char*)whh_f + j * 512;
  #pragma unroll
  for (int q = 0; q < 4; ++q){
    int c = kk * 4 + q;
    *(int4v*)(base + ((c ^ (j & 7)) << 4)) = *(int4v*)(o + q * 8);
  }
}

// ---------------------------------------------------------------------------
// K1: X (B,T,N) f32 -> Xp (B,N,T) bf16   (tile transpose through LDS)
__global__ __launch_bounds__(256) void k_xpose(const float* __restrict__ X,
                                               unsigned short* __restrict__ Xp){
  __shared__ float tile[128][65];
  int b = blockIdx.y, n0 = blockIdx.x * 64;
  int tid = threadIdx.x;
  int nloc = tid & 63, t0 = tid >> 6;
  const float* src = X + (size_t)b * TT * NN + n0 + nloc;
  #pragma unroll
  for (int r = 0; r < 32; ++r){
    int t = r * 4 + t0;
    tile[t][nloc] = src[(size_t)t * NN];
  }
  __syncthreads();
  int tl = tid & 127, nr0 = tid >> 7;
  unsigned short* dst = Xp + ((size_t)b * NN + n0) * TT + tl;
  #pragma unroll
  for (int r = 0; r < 32; ++r){
    int n = r * 2 + nr0;
    dst[(size_t)n * TT] = f2bf(tile[tl][n]);
  }
}

// ---------------------------------------------------------------------------
// K2: Q/K/V = Xp @ W^T per batch.  M=131072 rows, N=128, K=128.  blockIdx.y = mode.
__global__ __launch_bounds__(256) void k_qkv(const unsigned short* __restrict__ Xp,
      const unsigned short* __restrict__ Wqb, const unsigned short* __restrict__ Wkb,
      const unsigned short* __restrict__ Wvb,
      unsigned short* __restrict__ Qo, unsigned short* __restrict__ Ko,
      unsigned short* __restrict__ Vo){
  __shared__ __align__(16) char smem[32768 + 8192];
  unsigned short* Bs = (unsigned short*)smem;
  char* As = smem + 32768;
  char* Os = smem;
  int mode = blockIdx.y;
  const unsigned short* W = (mode == 0) ? Wqb : ((mode == 1) ? Wkb : Wvb);
  int m0 = blockIdx.x * 128;
  int tid = threadIdx.x;

  #pragma unroll
  for (int it = 0; it < 16; ++it){
    int c = it * 256 + tid;
    int j = c >> 5;
    int kc = (c & 31) << 2;
    short4v v = *(const short4v*)(W + j * 128 + kc);
    *(short4v*)((char*)Bs + j * 256 + ((kc * 2) ^ ((j & 7) << 4))) = v;
  }

  int lane = tid & 63, wv = tid >> 6;
  int wr = wv >> 1, wc = wv & 1;
  int l15 = lane & 15, g = lane >> 4;
  f32x4 zro = {0.f, 0.f, 0.f, 0.f};
  f32x4 acc[4][4];
  #pragma unroll
  for (int a = 0; a < 4; ++a)
    #pragma unroll
    for (int bq = 0; bq < 4; ++bq) acc[a][bq] = zro;

  int arow = tid >> 1, ahalf = (tid & 1) * 16;
  const unsigned short* Ap = Xp + (size_t)(m0 + arow) * 128;

  for (int ks = 0; ks < 4; ++ks){
    __syncthreads();
    {
      const unsigned short* s = Ap + ks * 32 + ahalf;
      char* base = As + arow * 64;
      int kb = ahalf * 2;
      int sw = (arow & 7) << 3;
      *(short4v*)(base + ((kb     ) ^ sw)) = *(const short4v*)(s);
      *(short4v*)(base + ((kb +  8) ^ sw)) = *(const short4v*)(s + 4);
      *(short4v*)(base + ((kb + 16) ^ sw)) = *(const short4v*)(s + 8);
      *(short4v*)(base + ((kb + 24) ^ sw)) = *(const short4v*)(s + 12);
    }
    __syncthreads();
    U8 af[4];
    #pragma unroll
    for (int mt = 0; mt < 4; ++mt){
      int ar = wr * 64 + mt * 16 + l15;
      const char* ab = As + ar * 64;
      int sw = (ar & 7) << 3;
      af[mt].h[0] = *(const short4v*)(ab + ((8 * g) ^ sw));
      af[mt].h[1] = *(const short4v*)(ab + ((8 * g + 32) ^ sw));
    }
    #pragma unroll
    for (int nt = 0; nt < 4; ++nt){
      int jr = wc * 64 + nt * 16 + l15;
      const char* bb = (const char*)Bs + jr * 256;
      int kb = ks * 64 + 8 * g, sw = (jr & 7) << 4;
      U8 bf;
      bf.h[0] = *(const short4v*)(bb + (kb ^ sw));
      bf.h[1] = *(const short4v*)(bb + ((kb + 32) ^ sw));
      #pragma unroll
      for (int mt = 0; mt < 4; ++mt)
        acc[mt][nt] = __builtin_amdgcn_mfma_f32_16x16x32_bf16(af[mt].v, bf.v, acc[mt][nt], 0, 0, 0);
    }
  }
  __syncthreads();
  float scale = (mode == 0) ? 0.0625f : 1.0f;
  #pragma unroll
  for (int mt = 0; mt < 4; ++mt)
    #pragma unroll
    for (int nt = 0; nt < 4; ++nt)
      #pragma unroll
      for (int r = 0; r < 4; ++r){
        int row = wr * 64 + mt * 16 + g * 4 + r;
        int col = wc * 64 + nt * 16 + l15;
        unsigned short hv = f2bf(acc[mt][nt][r] * scale);
        int addr = (mode == 2) ? (col * 256 + ((row * 2) ^ ((col & 7) << 4)))
                               : (row * 256 + ((col * 2) ^ ((row & 7) << 4)));
        *(unsigned short*)(Os + addr) = hv;
      }
  __syncthreads();
  int orow = tid >> 1, oseg = tid & 1;
  const char* srcrow = Os + orow * 256;
  unsigned short* dst;
  if (mode == 2){
    int bq = m0 >> 8, ibase = m0 & 255;
    dst = Vo + ((size_t)bq * 128 + orow) * 256 + ibase + oseg * 64;
  } else {
    dst = ((mode == 0) ? Qo : Ko) + (size_t)(m0 + orow) * 128 + oseg * 64;
  }
  #pragma unroll
  for (int c = 0; c < 8; ++c){
    int kb = oseg * 128 + c * 16;
    *(int4v*)((char*)dst + c * 16) = *(const int4v*)(srcrow + (kb ^ ((orow & 7) << 4)));
  }
}

// ---------------------------------------------------------------------------
// K3: fused attention per (b, 64-row i-tile). S=QK^T, softmax, Xa^T = V^T P^T.
__global__ __launch_bounds__(256) void k_attn(const unsigned short* __restrict__ Q,
        const unsigned short* __restrict__ K, const unsigned short* __restrict__ Vt,
        unsigned short* __restrict__ Xa){
  __shared__ __align__(16) char smem[16384 + 65536 + 32768 + 256];
  char* Qs = smem;
  char* Ks = smem + 16384;
  char* Ps = smem + 16384 + 65536;
  float* rden = (float*)(smem + 16384 + 65536 + 32768);
  int b = blockIdx.y, i0 = blockIdx.x * 64;
  int tid = threadIdx.x, lane = tid & 63, wv = tid >> 6;
  int l15 = lane & 15, g = lane >> 4;

  {
    int row = tid >> 2, q = tid & 3;
    const char* src = (const char*)(Q + ((size_t)b * 256 + i0 + row) * 128) + q * 64;
    char* dstr = Qs + row * 256;
    int sw = (row & 7) << 4;
    #pragma unroll
    for (int c = 0; c < 4; ++c){
      int kb = q * 64 + c * 16;
      *(int4v*)(dstr + (kb ^ sw)) = *(const int4v*)(src + c * 16);
    }
  }
  {
    const char* src = (const char*)(K + ((size_t)b * 256 + tid) * 128);
    char* dstr = Ks + tid * 256;
    int sw = (tid & 7) << 4;
    #pragma unroll
    for (int c = 0; c < 16; ++c)
      *(int4v*)(dstr + ((c * 16) ^ sw)) = *(const int4v*)(src + c * 16);
  }
  __syncthreads();

  f32x4 zro = {0.f, 0.f, 0.f, 0.f};
  f32x4 acc[16];
  #pragma unroll
  for (int nt = 0; nt < 16; ++nt) acc[nt] = zro;
  #pragma unroll
  for (int kk = 0; kk < 4; ++kk){
    int ar = wv * 16 + l15;
    const char* ab = Qs + ar * 256;
    int kb = kk * 64 + 8 * g, swa = (ar & 7) << 4;
    U8 a;
    a.h[0] = *(const short4v*)(ab + (kb ^ swa));
    a.h[1] = *(const short4v*)(ab + ((kb + 32) ^ swa));
    #pragma unroll
    for (int nt = 0; nt < 16; ++nt){
      int jr = nt * 16 + l15;
      const char* bb = Ks + jr * 256;
      int swb = (jr & 7) << 4;
      U8 bf;
      bf.h[0] = *(const short4v*)(bb + (kb ^ swb));
      bf.h[1] = *(const short4v*)(bb + ((kb + 32) ^ swb));
      acc[nt] = __builtin_amdgcn_mfma_f32_16x16x32_bf16(a.v, bf.v, acc[nt], 0, 0, 0);
    }
  }
  float mx[4], sm[4];
  #pragma unroll
  for (int r = 0; r < 4; ++r){
    float m = acc[0][r];
    #pragma unroll
    for (int nt = 1; nt < 16; ++nt) m = fmaxf(m, acc[nt][r]);
    #pragma unroll
    for (int s = 1; s < 16; s <<= 1) m = fmaxf(m, __shfl_xor(m, s));
    mx[r] = m;
  }
  #pragma unroll
  for (int r = 0; r < 4; ++r){
    float s = 0.f;
    #pragma unroll
    for (int nt = 0; nt < 16; ++nt){
      float p = __expf(acc[nt][r] - mx[r]);
      acc[nt][r] = p; s += p;
    }
    #pragma unroll
    for (int sd = 1; sd < 16; sd <<= 1) s += __shfl_xor(s, sd);
    sm[r] = s;
  }
  #pragma unroll
  for (int nt = 0; nt < 16; ++nt)
    #pragma unroll
    for (int r = 0; r < 4; ++r){
      int ir = wv * 16 + g * 4 + r;
      *(unsigned short*)(Ps + ir * 512 + ((nt * 16 + l15) * 2 ^ ((ir & 7) << 4))) = f2bf(acc[nt][r]);
    }
  #pragma unroll
  for (int r = 0; r < 4; ++r)
    if (l15 == r) rden[wv * 16 + g * 4 + r] = rcp_(sm[r]);
  __syncthreads();
  {
    int row = tid >> 1, half = tid & 1;
    const char* src = (const char*)(Vt + ((size_t)b * 128 + row) * 256) + half * 256;
    char* dstr = Ks + row * 512;
    int sw = (row & 7) << 4;
    #pragma unroll
    for (int c = 0; c < 16; ++c){
      int jb = half * 256 + c * 16;
      *(int4v*)(dstr + (jb ^ sw)) = *(const int4v*)(src + c * 16);
    }
  }
  __syncthreads();

  f32x4 acc2[2][4];
  #pragma unroll
  for (int mt = 0; mt < 2; ++mt)
    #pragma unroll
    for (int nt = 0; nt < 4; ++nt) acc2[mt][nt] = zro;
  #pragma unroll
  for (int kk = 0; kk < 8; ++kk){
    int kb = kk * 64 + 8 * g;
    U8 bfr[4];
    #pragma unroll
    for (int nt = 0; nt < 4; ++nt){
      int ir = nt * 16 + l15;
      const char* pb = Ps + ir * 512;
      int sw = (ir & 7) << 4;
      bfr[nt].h[0] = *(const short4v*)(pb + (kb ^ sw));
      bfr[nt].h[1] = *(const short4v*)(pb + ((kb + 32) ^ sw));
    }
    #pragma unroll
    for (int mt = 0; mt < 2; ++mt){
      int tr = wv * 32 + mt * 16 + l15;
      const char* ab = Ks + tr * 512;
      int sw = (tr & 7) << 4;
      U8 a;
      a.h[0] = *(const short4v*)(ab + (kb ^ sw));
      a.h[1] = *(const short4v*)(ab + ((kb + 32) ^ sw));
      #pragma unroll
      for (int nt = 0; nt < 4; ++nt)
        acc2[mt][nt] = __builtin_amdgcn_mfma_f32_16x16x32_bf16(a.v, bfr[nt].v, acc2[mt][nt], 0, 0, 0);
    }
  }
  #pragma unroll
  for (int nt = 0; nt < 4; ++nt){
    float rd = rden[nt * 16 + l15];
    #pragma unroll
    for (int mt = 0; mt < 2; ++mt)
      #pragma unroll
      for (int r = 0; r < 4; ++r){
        int t = wv * 32 + mt * 16 + g * 4 + r;
        int i = i0 + nt * 16 + l15;
        Xa[((size_t)b * 128 + t) * 256 + i] = f2bf(acc2[mt][nt][r] * rd);
      }
  }
}

// ---------------------------------------------------------------------------
// K4: Wx = Xa @ W_ih^T + bias, written time-major (T,B,4H).
template<bool WXF32>
__global__ __launch_bounds__(256) void k_wx(const unsigned short* __restrict__ Xa,
        const unsigned short* __restrict__ Wih, const float* __restrict__ bias,
        void* __restrict__ WxT){
  __shared__ __align__(16) char smem[65536 + 8192];
  char* Bsm = smem;
  char* As = smem + 65536;
  int bidx = blockIdx.x;
  int j0 = blockIdx.y * 128;
  int tid = threadIdx.x;
  {
    int row = tid >> 1, half = tid & 1;
    const char* src = (const char*)(Wih + (size_t)(j0 + row) * 256) + half * 256;
    char* dstr = Bsm + row * 512;
    int sw = (row & 7) << 4;
    #pragma unroll
    for (int c = 0; c < 16; ++c){
      int kb = half * 256 + c * 16;
      *(int4v*)(dstr + (kb ^ sw)) = *(const int4v*)(src + c * 16);
    }
  }
  int lane = tid & 63, wv = tid >> 6, wr = wv >> 1, wc = wv & 1;
  int l15 = lane & 15, g = lane >> 4;
  f32x4 zro = {0.f, 0.f, 0.f, 0.f};
  f32x4 acc[4][4];
  #pragma unroll
  for (int a = 0; a < 4; ++a)
    #pragma unroll
    for (int bq = 0; bq < 4; ++bq) acc[a][bq] = zro;
  int arow = tid >> 1, ahalf = (tid & 1) * 16;
  const unsigned short* Ap = Xa + (size_t)(bidx * 128 + arow) * 256;
  for (int ks = 0; ks < 8; ++ks){
    __syncthreads();
    {
      const unsigned short* s = Ap + ks * 32 + ahalf;
      char* base = As + arow * 64;
      int kb = ahalf * 2, sw = (arow & 7) << 3;
      *(short4v*)(base + ((kb     ) ^ sw)) = *(const short4v*)(s);
      *(short4v*)(base + ((kb +  8) ^ sw)) = *(const short4v*)(s + 4);
      *(short4v*)(base + ((kb + 16) ^ sw)) = *(const short4v*)(s + 8);
      *(short4v*)(base + ((kb + 24) ^ sw)) = *(const short4v*)(s + 12);
    }
    __syncthreads();
    U8 af[4];
    #pragma unroll
    for (int mt = 0; mt < 4; ++mt){
      int ar = wr * 64 + mt * 16 + l15;
      const char* ab = As + ar * 64;
      int sw = (ar & 7) << 3;
      af[mt].h[0] = *(const short4v*)(ab + ((8 * g) ^ sw));
      af[mt].h[1] = *(const short4v*)(ab + ((8 * g + 32) ^ sw));
    }
    #pragma unroll
    for (int nt = 0; nt < 4; ++nt){
      int jr = wc * 64 + nt * 16 + l15;
      const char* bb = Bsm + jr * 512;
      int kb = ks * 64 + 8 * g, sw = (jr & 7) << 4;
      U8 bf;
      bf.h[0] = *(const short4v*)(bb + (kb ^ sw));
      bf.h[1] = *(const short4v*)(bb + ((kb + 32) ^ sw));
      #pragma unroll
      for (int mt = 0; mt < 4; ++mt)
        acc[mt][nt] = __builtin_amdgcn_mfma_f32_16x16x32_bf16(af[mt].v, bf.v, acc[mt][nt], 0, 0, 0);
    }
  }
  #pragma unroll
  for (int nt = 0; nt < 4; ++nt){
    int j = j0 + wc * 64 + nt * 16 + l15;
    float bs = bias[j];
    #pragma unroll
    for (int mt = 0; mt < 4; ++mt)
      #pragma unroll
      for (int r = 0; r < 4; ++r){
        int t = wr * 64 + mt * 16 + g * 4 + r;
        float v = acc[mt][nt][r] + bs;
        size_t o = ((size_t)t * 512 + bidx) * 1024 + j;
        if (WXF32) ((float*)WxT)[o] = v;
        else       ((unsigned short*)WxT)[o] = f2bf(v);
      }
  }
}

// ---------------------------------------------------------------------------
// K5 v3: LSTM, full-streaming. 64 blocks x 512 thr (8 waves), 8 batches, 128 steps.
// Per step: 8 pieces of 64KB of W_hh streamed L2->LDS (global_load_lds, 2x64KB dbuf).
// Piece p = j-rows [p*128,(p+1)*128) = acc tile p = gate (p>>1), j-block (p&1)*128.
// h hi/lo packed in MFMA M-dim (rows 0-7 / 8-15); gate = keep + shfl_xor(send,32).
template<bool WXF32>
__global__ __launch_bounds__(512, 2) void k_lstm3(const void* __restrict__ WxT,
        const unsigned short* __restrict__ whh_f, float* __restrict__ out){
  __shared__ __align__(16) char smem[131072 + 16384];
  char* WB = smem;            // two 64KB W piece buffers (piece q -> buffer q&1)
  char* HS = smem + 131072;   // h frag-major: [buf2][kk 0..7][row 0..15][chunk][16B]
  int tid = threadIdx.x, lane = tid & 63, wv = tid >> 6;
  int l15 = lane & 15, g = lane >> 4;
  int half = g >> 1;                 // which j-block (0: +0, 1: +128) this lane finalizes
  bool hiL = (g < 2);                // acc rows 0-7 (hi part) live on lanes g<2
  int b0 = blockIdx.x * 8;

  // ---- zero h double-buffers
  {
    int4v z = {0, 0, 0, 0};
    *(int4v*)(HS + tid * 32) = z;
    *(int4v*)(HS + tid * 32 + 16) = z;
  }
  float cst[4] = {0.f, 0.f, 0.f, 0.f};
  f32x4 acc[8];
  // ---- C-init for t=0: rows 0-7 (g<2) get Wx, rows 8-15 get 0
  #pragma unroll
  for (int tile = 0; tile < 8; ++tile){
    int j = (tile >> 1) * 256 + (tile & 1) * 128 + wv * 16 + l15;
    #pragma unroll
    for (int r = 0; r < 4; ++r){
      float v = 0.f;
      if (hiL){
        size_t o = (size_t)(b0 + g * 4 + r) * 1024 + j;
        v = WXF32 ? ((const float*)WxT)[o] : bf2f(((const unsigned short*)WxT)[o]);
      }
      acc[tile][r] = v;
    }
  }
  // ---- preload piece 0 into WB[0]
  {
    const char* gsrc = (const char*)whh_f + tid * 16;
    char* ldst = WB + tid * 16;
    #pragma unroll
    for (int i = 0; i < 8; ++i)
      g2l16(gsrc + i * 8192, ldst + i * 8192);
  }
  asm volatile("s_waitcnt vmcnt(0)" ::: "memory");
  __syncthreads();

  int cur = 0;
  int jr = wv * 16 + l15;                      // within-piece j row
  int jsw = (jr & 7);                          // read-side chunk swizzle
  int aoff = l15 * 64 + (((g ^ (l15 >> 2)) & 3) << 4);
  #pragma unroll 1
  for (int t = 0; t < 128; ++t){
    // ---- A-frags for this step (8 x b128 from HS[cur])
    U8 aF[8];
    #pragma unroll
    for (int kk = 0; kk < 8; ++kk)
      aF[kk].i = *(const int4v*)(HS + cur * 8192 + kk * 1024 + aoff);
    // ---- 8 pieces: stream next, compute current
    #pragma unroll 1
    for (int p = 0; p < 8; ++p){
      { // issue loads for piece p+1 (p==7 -> piece 0 for next step) into WB[p^1... (p+1)&1]
        int q = (p + 1) & 7;
        const char* gsrc = (const char*)whh_f + q * 65536 + tid * 16;
        char* ldst = WB + (q & 1) * 65536 + tid * 16;
        #pragma unroll
        for (int i = 0; i < 8; ++i)
          g2l16(gsrc + i * 8192, ldst + i * 8192);
      }
      const char* wb = WB + (p & 1) * 65536 + jr * 512;
      #pragma unroll
      for (int kk = 0; kk < 8; ++kk){
        U8 b;
        b.i = *(const int4v*)(wb + (((kk * 4 + g) ^ jsw) << 4));
        acc[p] = __builtin_amdgcn_mfma_f32_16x16x32_bf16(aF[kk].v, b.v, acc[p], 0, 0, 0);
      }
      asm volatile("s_waitcnt vmcnt(0)" ::: "memory");
      __syncthreads();
    }
    // ---- gate phase. Lane keeps its j-block's tile, SENDS the opposite tile
    // across the hi/lo shfl (partner g^2 holds the other M-rows of both tiles).
    int nb = cur ^ 1;
    #pragma unroll
    for (int r = 0; r < 4; ++r){
      float val[4];
      #pragma unroll
      for (int gate = 0; gate < 4; ++gate){
        float v0 = acc[gate * 2][r];
        float v1 = acc[gate * 2 + 1][r];
        float keep = half ? v1 : v0;
        float send = half ? v0 : v1;
        val[gate] = keep + __shfl_xor(send, 32);
      }
      // prefetch Wx(t+1) into freed acc[.][r]
      if (t < 127){
        #pragma unroll
        for (int tile = 0; tile < 8; ++tile){
          int j = (tile >> 1) * 256 + (tile & 1) * 128 + wv * 16 + l15;
          float v = 0.f;
          if (hiL){
            size_t o = ((size_t)(t + 1) * 512 + b0 + g * 4 + r) * 1024 + j;
            v = WXF32 ? ((const float*)WxT)[o] : bf2f(((const unsigned short*)WxT)[o]);
          }
          acc[tile][r] = v;
        }
      }
      float gi = sigm(val[0]);
      float gf = sigm(val[1]);
      float gg = tanhf_(val[2]);
      float go = sigm(val[3]);
      float c = gf * cst[r] + gi * gg;
      cst[r] = c;
      float h = go * tanhf_(c);
      int batch = (g & 1) * 4 + r;
      int jc = wv * 16 + half * 128 + l15;
      out[((size_t)(b0 + batch) * 128 + t) * 256 + jc] = h;
      unsigned short h_hi = f2bf(h);
      unsigned short h_lo = f2bf(h - bf2f(h_hi));
      int kkw = (wv >> 1) + half * 4;
      char* hw = HS + nb * 8192 + kkw * 1024;
      int ga = l15 >> 2, inb = (l15 & 3) * 2 + (wv & 1) * 8;
      *(unsigned short*)(hw + batch * 64 + ((ga ^ ((batch >> 2) & 3)) << 4) + inb) = h_hi;
      int rowl = batch + 8;
      *(unsigned short*)(hw + rowl * 64 + ((ga ^ ((rowl >> 2) & 3)) << 4) + inb) = h_lo;
    }
    __syncthreads();
    cur = nb;
  }
}

// ---------------------------------------------------------------------------
extern "C" void kernel_launch(void* const* d_in, const int* in_sizes, int n_in,
                              void* d_out, int out_size, void* d_ws, size_t ws_size,
                              hipStream_t stream){
  (void)in_sizes; (void)n_in; (void)out_size;
  const float* X   = (const float*)d_in[0];
  const float* Wq  = (const float*)d_in[1];
  const float* Wk  = (const float*)d_in[2];
  const float* Wv  = (const float*)d_in[3];
  const float* Wih = (const float*)d_in[4];
  const float* Whh = (const float*)d_in[5];
  const float* bih = (const float*)d_in[6];
  const float* bhh = (const float*)d_in[7];
  float* out = (float*)d_out;
  char* ws = (char*)d_ws;

  const size_t SZ  = 33554432ULL;        // one (B,N,T) bf16 buffer
  const size_t WXF = 268435456ULL;       // Wx f32 (T,B,4H)
  const size_t WTS = 1150976ULL;         // casted weights + bias
  bool wxf32 = ws_size >= WXF + SZ + WTS;
  size_t wxb = wxf32 ? WXF : WXF / 2;

  unsigned short* p_xp = (unsigned short*)ws;
  unsigned short* p_q  = (unsigned short*)(ws + SZ);
  unsigned short* p_k  = (unsigned short*)(ws + 2 * SZ);
  unsigned short* p_vt = (unsigned short*)(ws + 3 * SZ);
  void* p_wx = (void*)ws;
  char* p = ws + wxb;
  unsigned short* p_xa  = (unsigned short*)p; p += SZ;
  unsigned short* p_wqb = (unsigned short*)p; p += 32768;
  unsigned short* p_wkb = (unsigned short*)p; p += 32768;
  unsigned short* p_wvb = (unsigned short*)p; p += 32768;
  unsigned short* p_wihb= (unsigned short*)p; p += 524288;
  unsigned short* p_whhf= (unsigned short*)p; p += 524288;
  float* p_bias = (float*)p;

  k_prep<<<1024, 256, 0, stream>>>(Wq, Wk, Wv, Wih, bih, bhh,
                                   p_wqb, p_wkb, p_wvb, p_wihb, p_bias);
  k_prep2<<<32, 256, 0, stream>>>(Whh, p_whhf);
  k_xpose<<<dim3(4, 512), 256, 0, stream>>>(X, p_xp);
  k_qkv<<<dim3(1024, 3), 256, 0, stream>>>(p_xp, p_wqb, p_wkb, p_wvb, p_q, p_k, p_vt);
  k_attn<<<dim3(4, 512), 256, 0, stream>>>(p_q, p_k, p_vt, p_xa);
  if (wxf32){
    k_wx<true><<<dim3(512, 8), 256, 0, stream>>>(p_xa, p_wihb, p_bias, p_wx);
    k_lstm3<true><<<64, 512, 0, stream>>>(p_wx, p_whhf, out);
  } else {
    k_wx<false><<<dim3(512, 8), 256, 0, stream>>>(p_xa, p_wihb, p_bias, p_wx);
    k_lstm3<false><<<64, 512, 0, stream>>>(p_wx, p_whhf, out);
  }
}

// Round 5
// 1638.912 us; speedup vs baseline: 1.6277x; 1.6277x over previous
//
#include <hip/hip_runtime.h>
#include <hip/hip_bf16.h>
#include <stdint.h>

// Encoder: X->(transpose)->QKV GEMMs -> attention(softmax) -> Wx GEMM -> 128-step LSTM
// B=512 T=128 N=256 H=256, all inputs f32, output f32 (B,T,H).
// Round 5: k_lstm4 — W_hh sharded across 4-CU groups (64 VGPR/wave of B-frags, no
// streaming, no LDS W). h exchanged per step via agent-scope atomics + flag sync.
// (R4 lesson: per-CU L2 BW ~56 B/cy makes per-step W streaming a ~9.4k cy/step floor.)

#define DI __device__ __forceinline__

typedef __attribute__((ext_vector_type(8))) short bf16x8;   // 8 bf16 = 4 VGPR (MFMA A/B frag)
typedef __attribute__((ext_vector_type(4))) short short4v;  // 8B
typedef __attribute__((ext_vector_type(4))) float f32x4;    // MFMA C/D frag
typedef __attribute__((ext_vector_type(4))) int int4v;      // 16B

union U8 { bf16x8 v; short4v h[2]; int4v i; };

DI unsigned short f2bf(float x){
  union { float f; unsigned u; } v; v.f = x;
  unsigned r = v.u + 0x7fffu + ((v.u >> 16) & 1u);
  return (unsigned short)(r >> 16);
}
DI float bf2f(unsigned short x){
  union { unsigned u; float f; } v; v.u = ((unsigned)x) << 16; return v.f;
}
DI float rcp_(float x){ return __builtin_amdgcn_rcpf(x); }
DI float sigm(float x){ return rcp_(1.0f + __expf(-x)); }
DI float tanhf_(float x){ return 1.0f - 2.0f * rcp_(1.0f + __expf(2.0f * x)); }

#define BB 512
#define TT 128
#define NN 256
#define HH 256

// ---------------------------------------------------------------------------
// K0: cast weights to bf16, fuse biases, zero the group sync flags
__global__ void k_prep(const float* __restrict__ Wq, const float* __restrict__ Wk,
                       const float* __restrict__ Wv, const float* __restrict__ Wih,
                       const float* __restrict__ bih, const float* __restrict__ bhh,
                       unsigned short* __restrict__ wqb, unsigned short* __restrict__ wkb,
                       unsigned short* __restrict__ wvb, unsigned short* __restrict__ wihb,
                       float* __restrict__ bias, int* __restrict__ flags){
  int i = blockIdx.x * 256 + threadIdx.x;
  if (i < 16384){ wqb[i] = f2bf(Wq[i]); wkb[i] = f2bf(Wk[i]); wvb[i] = f2bf(Wv[i]); }
  if (i < 262144){ wihb[i] = f2bf(Wih[i]); }
  if (i < 1024){ bias[i] = bih[i] + bhh[i]; }
  if (i < 64){ flags[i] = 0; }
}

// K0b: W_hh -> fragment-major bf16: frag (j, kk, g) holds
// W[j][kk*32+4g+{0..3}] , W[j][kk*32+16+4g+{0..3}].  Byte = j*512 + kk*64 + g*16.
__global__ void k_prep2(const float* __restrict__ Whh, unsigned short* __restrict__ whh_f){
  int idx = blockIdx.x * 256 + threadIdx.x;   // 8192 = 1024 j x 8 kk
  int j = idx >> 3, kk = idx & 7;
  const float* src = Whh + j * 256 + kk * 32;
  unsigned short o[32];
  #pragma unroll
  for (int g = 0; g < 4; ++g)
    #pragma unroll
    for (int e = 0; e < 4; ++e){
      o[g * 8 + e]     = f2bf(src[4 * g + e]);
      o[g * 8 + 4 + e] = f2bf(src[16 + 4 * g + e]);
    }
  int4v* dst = (int4v*)((char*)whh_f + j * 512 + kk * 64);
  #pragma unroll
  for (int q = 0; q < 4; ++q) dst[q] = *(int4v*)(o + q * 8);
}

// ---------------------------------------------------------------------------
// K1: X (B,T,N) f32 -> Xp (B,N,T) bf16   (tile transpose through LDS)
__global__ __launch_bounds__(256) void k_xpose(const float* __restrict__ X,
                                               unsigned short* __restrict__ Xp){
  __shared__ float tile[128][65];
  int b = blockIdx.y, n0 = blockIdx.x * 64;
  int tid = threadIdx.x;
  int nloc = tid & 63, t0 = tid >> 6;
  const float* src = X + (size_t)b * TT * NN + n0 + nloc;
  #pragma unroll
  for (int r = 0; r < 32; ++r){
    int t = r * 4 + t0;
    tile[t][nloc] = src[(size_t)t * NN];
  }
  __syncthreads();
  int tl = tid & 127, nr0 = tid >> 7;
  unsigned short* dst = Xp + ((size_t)b * NN + n0) * TT + tl;
  #pragma unroll
  for (int r = 0; r < 32; ++r){
    int n = r * 2 + nr0;
    dst[(size_t)n * TT] = f2bf(tile[tl][n]);
  }
}

// ---------------------------------------------------------------------------
// K2: Q/K/V = Xp @ W^T per batch.  M=131072 rows, N=128, K=128.  blockIdx.y = mode.
__global__ __launch_bounds__(256) void k_qkv(const unsigned short* __restrict__ Xp,
      const unsigned short* __restrict__ Wqb, const unsigned short* __restrict__ Wkb,
      const unsigned short* __restrict__ Wvb,
      unsigned short* __restrict__ Qo, unsigned short* __restrict__ Ko,
      unsigned short* __restrict__ Vo){
  __shared__ __align__(16) char smem[32768 + 8192];
  unsigned short* Bs = (unsigned short*)smem;
  char* As = smem + 32768;
  char* Os = smem;
  int mode = blockIdx.y;
  const unsigned short* W = (mode == 0) ? Wqb : ((mode == 1) ? Wkb : Wvb);
  int m0 = blockIdx.x * 128;
  int tid = threadIdx.x;

  #pragma unroll
  for (int it = 0; it < 16; ++it){
    int c = it * 256 + tid;
    int j = c >> 5;
    int kc = (c & 31) << 2;
    short4v v = *(const short4v*)(W + j * 128 + kc);
    *(short4v*)((char*)Bs + j * 256 + ((kc * 2) ^ ((j & 7) << 4))) = v;
  }

  int lane = tid & 63, wv = tid >> 6;
  int wr = wv >> 1, wc = wv & 1;
  int l15 = lane & 15, g = lane >> 4;
  f32x4 zro = {0.f, 0.f, 0.f, 0.f};
  f32x4 acc[4][4];
  #pragma unroll
  for (int a = 0; a < 4; ++a)
    #pragma unroll
    for (int bq = 0; bq < 4; ++bq) acc[a][bq] = zro;

  int arow = tid >> 1, ahalf = (tid & 1) * 16;
  const unsigned short* Ap = Xp + (size_t)(m0 + arow) * 128;

  for (int ks = 0; ks < 4; ++ks){
    __syncthreads();
    {
      const unsigned short* s = Ap + ks * 32 + ahalf;
      char* base = As + arow * 64;
      int kb = ahalf * 2;
      int sw = (arow & 7) << 3;
      *(short4v*)(base + ((kb     ) ^ sw)) = *(const short4v*)(s);
      *(short4v*)(base + ((kb +  8) ^ sw)) = *(const short4v*)(s + 4);
      *(short4v*)(base + ((kb + 16) ^ sw)) = *(const short4v*)(s + 8);
      *(short4v*)(base + ((kb + 24) ^ sw)) = *(const short4v*)(s + 12);
    }
    __syncthreads();
    U8 af[4];
    #pragma unroll
    for (int mt = 0; mt < 4; ++mt){
      int ar = wr * 64 + mt * 16 + l15;
      const char* ab = As + ar * 64;
      int sw = (ar & 7) << 3;
      af[mt].h[0] = *(const short4v*)(ab + ((8 * g) ^ sw));
      af[mt].h[1] = *(const short4v*)(ab + ((8 * g + 32) ^ sw));
    }
    #pragma unroll
    for (int nt = 0; nt < 4; ++nt){
      int jr = wc * 64 + nt * 16 + l15;
      const char* bb = (const char*)Bs + jr * 256;
      int kb = ks * 64 + 8 * g, sw = (jr & 7) << 4;
      U8 bf;
      bf.h[0] = *(const short4v*)(bb + (kb ^ sw));
      bf.h[1] = *(const short4v*)(bb + ((kb + 32) ^ sw));
      #pragma unroll
      for (int mt = 0; mt < 4; ++mt)
        acc[mt][nt] = __builtin_amdgcn_mfma_f32_16x16x32_bf16(af[mt].v, bf.v, acc[mt][nt], 0, 0, 0);
    }
  }
  __syncthreads();
  float scale = (mode == 0) ? 0.0625f : 1.0f;
  #pragma unroll
  for (int mt = 0; mt < 4; ++mt)
    #pragma unroll
    for (int nt = 0; nt < 4; ++nt)
      #pragma unroll
      for (int r = 0; r < 4; ++r){
        int row = wr * 64 + mt * 16 + g * 4 + r;
        int col = wc * 64 + nt * 16 + l15;
        unsigned short hv = f2bf(acc[mt][nt][r] * scale);
        int addr = (mode == 2) ? (col * 256 + ((row * 2) ^ ((col & 7) << 4)))
                               : (row * 256 + ((col * 2) ^ ((row & 7) << 4)));
        *(unsigned short*)(Os + addr) = hv;
      }
  __syncthreads();
  int orow = tid >> 1, oseg = tid & 1;
  const char* srcrow = Os + orow * 256;
  unsigned short* dst;
  if (mode == 2){
    int bq = m0 >> 8, ibase = m0 & 255;
    dst = Vo + ((size_t)bq * 128 + orow) * 256 + ibase + oseg * 64;
  } else {
    dst = ((mode == 0) ? Qo : Ko) + (size_t)(m0 + orow) * 128 + oseg * 64;
  }
  #pragma unroll
  for (int c = 0; c < 8; ++c){
    int kb = oseg * 128 + c * 16;
    *(int4v*)((char*)dst + c * 16) = *(const int4v*)(srcrow + (kb ^ ((orow & 7) << 4)));
  }
}

// ---------------------------------------------------------------------------
// K3: fused attention per (b, 64-row i-tile). S=QK^T, softmax, Xa^T = V^T P^T.
__global__ __launch_bounds__(256) void k_attn(const unsigned short* __restrict__ Q,
        const unsigned short* __restrict__ K, const unsigned short* __restrict__ Vt,
        unsigned short* __restrict__ Xa){
  __shared__ __align__(16) char smem[16384 + 65536 + 32768 + 256];
  char* Qs = smem;
  char* Ks = smem + 16384;
  char* Ps = smem + 16384 + 65536;
  float* rden = (float*)(smem + 16384 + 65536 + 32768);
  int b = blockIdx.y, i0 = blockIdx.x * 64;
  int tid = threadIdx.x, lane = tid & 63, wv = tid >> 6;
  int l15 = lane & 15, g = lane >> 4;

  {
    int row = tid >> 2, q = tid & 3;
    const char* src = (const char*)(Q + ((size_t)b * 256 + i0 + row) * 128) + q * 64;
    char* dstr = Qs + row * 256;
    int sw = (row & 7) << 4;
    #pragma unroll
    for (int c = 0; c < 4; ++c){
      int kb = q * 64 + c * 16;
      *(int4v*)(dstr + (kb ^ sw)) = *(const int4v*)(src + c * 16);
    }
  }
  {
    const char* src = (const char*)(K + ((size_t)b * 256 + tid) * 128);
    char* dstr = Ks + tid * 256;
    int sw = (tid & 7) << 4;
    #pragma unroll
    for (int c = 0; c < 16; ++c)
      *(int4v*)(dstr + ((c * 16) ^ sw)) = *(const int4v*)(src + c * 16);
  }
  __syncthreads();

  f32x4 zro = {0.f, 0.f, 0.f, 0.f};
  f32x4 acc[16];
  #pragma unroll
  for (int nt = 0; nt < 16; ++nt) acc[nt] = zro;
  #pragma unroll
  for (int kk = 0; kk < 4; ++kk){
    int ar = wv * 16 + l15;
    const char* ab = Qs + ar * 256;
    int kb = kk * 64 + 8 * g, swa = (ar & 7) << 4;
    U8 a;
    a.h[0] = *(const short4v*)(ab + (kb ^ swa));
    a.h[1] = *(const short4v*)(ab + ((kb + 32) ^ swa));
    #pragma unroll
    for (int nt = 0; nt < 16; ++nt){
      int jr = nt * 16 + l15;
      const char* bb = Ks + jr * 256;
      int swb = (jr & 7) << 4;
      U8 bf;
      bf.h[0] = *(const short4v*)(bb + (kb ^ swb));
      bf.h[1] = *(const short4v*)(bb + ((kb + 32) ^ swb));
      acc[nt] = __builtin_amdgcn_mfma_f32_16x16x32_bf16(a.v, bf.v, acc[nt], 0, 0, 0);
    }
  }
  float mx[4], sm[4];
  #pragma unroll
  for (int r = 0; r < 4; ++r){
    float m = acc[0][r];
    #pragma unroll
    for (int nt = 1; nt < 16; ++nt) m = fmaxf(m, acc[nt][r]);
    #pragma unroll
    for (int s = 1; s < 16; s <<= 1) m = fmaxf(m, __shfl_xor(m, s));
    mx[r] = m;
  }
  #pragma unroll
  for (int r = 0; r < 4; ++r){
    float s = 0.f;
    #pragma unroll
    for (int nt = 0; nt < 16; ++nt){
      float p = __expf(acc[nt][r] - mx[r]);
      acc[nt][r] = p; s += p;
    }
    #pragma unroll
    for (int sd = 1; sd < 16; sd <<= 1) s += __shfl_xor(s, sd);
    sm[r] = s;
  }
  #pragma unroll
  for (int nt = 0; nt < 16; ++nt)
    #pragma unroll
    for (int r = 0; r < 4; ++r){
      int ir = wv * 16 + g * 4 + r;
      *(unsigned short*)(Ps + ir * 512 + ((nt * 16 + l15) * 2 ^ ((ir & 7) << 4))) = f2bf(acc[nt][r]);
    }
  #pragma unroll
  for (int r = 0; r < 4; ++r)
    if (l15 == r) rden[wv * 16 + g * 4 + r] = rcp_(sm[r]);
  __syncthreads();
  {
    int row = tid >> 1, half = tid & 1;
    const char* src = (const char*)(Vt + ((size_t)b * 128 + row) * 256) + half * 256;
    char* dstr = Ks + row * 512;
    int sw = (row & 7) << 4;
    #pragma unroll
    for (int c = 0; c < 16; ++c){
      int jb = half * 256 + c * 16;
      *(int4v*)(dstr + (jb ^ sw)) = *(const int4v*)(src + c * 16);
    }
  }
  __syncthreads();

  f32x4 acc2[2][4];
  #pragma unroll
  for (int mt = 0; mt < 2; ++mt)
    #pragma unroll
    for (int nt = 0; nt < 4; ++nt) acc2[mt][nt] = zro;
  #pragma unroll
  for (int kk = 0; kk < 8; ++kk){
    int kb = kk * 64 + 8 * g;
    U8 bfr[4];
    #pragma unroll
    for (int nt = 0; nt < 4; ++nt){
      int ir = nt * 16 + l15;
      const char* pb = Ps + ir * 512;
      int sw = (ir & 7) << 4;
      bfr[nt].h[0] = *(const short4v*)(pb + (kb ^ sw));
      bfr[nt].h[1] = *(const short4v*)(pb + ((kb + 32) ^ sw));
    }
    #pragma unroll
    for (int mt = 0; mt < 2; ++mt){
      int tr = wv * 32 + mt * 16 + l15;
      const char* ab = Ks + tr * 512;
      int sw = (tr & 7) << 4;
      U8 a;
      a.h[0] = *(const short4v*)(ab + (kb ^ sw));
      a.h[1] = *(const short4v*)(ab + ((kb + 32) ^ sw));
      #pragma unroll
      for (int nt = 0; nt < 4; ++nt)
        acc2[mt][nt] = __builtin_amdgcn_mfma_f32_16x16x32_bf16(a.v, bfr[nt].v, acc2[mt][nt], 0, 0, 0);
    }
  }
  #pragma unroll
  for (int nt = 0; nt < 4; ++nt){
    float rd = rden[nt * 16 + l15];
    #pragma unroll
    for (int mt = 0; mt < 2; ++mt)
      #pragma unroll
      for (int r = 0; r < 4; ++r){
        int t = wv * 32 + mt * 16 + g * 4 + r;
        int i = i0 + nt * 16 + l15;
        Xa[((size_t)b * 128 + t) * 256 + i] = f2bf(acc2[mt][nt][r] * rd);
      }
  }
}

// ---------------------------------------------------------------------------
// K4: Wx = Xa @ W_ih^T + bias, written time-major (T,B,4H).
template<bool WXF32>
__global__ __launch_bounds__(256) void k_wx(const unsigned short* __restrict__ Xa,
        const unsigned short* __restrict__ Wih, const float* __restrict__ bias,
        void* __restrict__ WxT){
  __shared__ __align__(16) char smem[65536 + 8192];
  char* Bsm = smem;
  char* As = smem + 65536;
  int bidx = blockIdx.x;
  int j0 = blockIdx.y * 128;
  int tid = threadIdx.x;
  {
    int row = tid >> 1, half = tid & 1;
    const char* src = (const char*)(Wih + (size_t)(j0 + row) * 256) + half * 256;
    char* dstr = Bsm + row * 512;
    int sw = (row & 7) << 4;
    #pragma unroll
    for (int c = 0; c < 16; ++c){
      int kb = half * 256 + c * 16;
      *(int4v*)(dstr + (kb ^ sw)) = *(const int4v*)(src + c * 16);
    }
  }
  int lane = tid & 63, wv = tid >> 6, wr = wv >> 1, wc = wv & 1;
  int l15 = lane & 15, g = lane >> 4;
  f32x4 zro = {0.f, 0.f, 0.f, 0.f};
  f32x4 acc[4][4];
  #pragma unroll
  for (int a = 0; a < 4; ++a)
    #pragma unroll
    for (int bq = 0; bq < 4; ++bq) acc[a][bq] = zro;
  int arow = tid >> 1, ahalf = (tid & 1) * 16;
  const unsigned short* Ap = Xa + (size_t)(bidx * 128 + arow) * 256;
  for (int ks = 0; ks < 8; ++ks){
    __syncthreads();
    {
      const unsigned short* s = Ap + ks * 32 + ahalf;
      char* base = As + arow * 64;
      int kb = ahalf * 2, sw = (arow & 7) << 3;
      *(short4v*)(base + ((kb     ) ^ sw)) = *(const short4v*)(s);
      *(short4v*)(base + ((kb +  8) ^ sw)) = *(const short4v*)(s + 4);
      *(short4v*)(base + ((kb + 16) ^ sw)) = *(const short4v*)(s + 8);
      *(short4v*)(base + ((kb + 24) ^ sw)) = *(const short4v*)(s + 12);
    }
    __syncthreads();
    U8 af[4];
    #pragma unroll
    for (int mt = 0; mt < 4; ++mt){
      int ar = wr * 64 + mt * 16 + l15;
      const char* ab = As + ar * 64;
      int sw = (ar & 7) << 3;
      af[mt].h[0] = *(const short4v*)(ab + ((8 * g) ^ sw));
      af[mt].h[1] = *(const short4v*)(ab + ((8 * g + 32) ^ sw));
    }
    #pragma unroll
    for (int nt = 0; nt < 4; ++nt){
      int jr = wc * 64 + nt * 16 + l15;
      const char* bb = Bsm + jr * 512;
      int kb = ks * 64 + 8 * g, sw = (jr & 7) << 4;
      U8 bf;
      bf.h[0] = *(const short4v*)(bb + (kb ^ sw));
      bf.h[1] = *(const short4v*)(bb + ((kb + 32) ^ sw));
      #pragma unroll
      for (int mt = 0; mt < 4; ++mt)
        acc[mt][nt] = __builtin_amdgcn_mfma_f32_16x16x32_bf16(af[mt].v, bf.v, acc[mt][nt], 0, 0, 0);
    }
  }
  #pragma unroll
  for (int nt = 0; nt < 4; ++nt){
    int j = j0 + wc * 64 + nt * 16 + l15;
    float bs = bias[j];
    #pragma unroll
    for (int mt = 0; mt < 4; ++mt)
      #pragma unroll
      for (int r = 0; r < 4; ++r){
        int t = wr * 64 + mt * 16 + g * 4 + r;
        float v = acc[mt][nt][r] + bs;
        size_t o = ((size_t)t * 512 + bidx) * 1024 + j;
        if (WXF32) ((float*)WxT)[o] = v;
        else       ((unsigned short*)WxT)[o] = f2bf(v);
      }
  }
}

// ---------------------------------------------------------------------------
// K5 v4: LSTM, group-sharded W. 256 blocks x 512 thr; group of 4 blocks = 8 batches;
// member m owns gate-columns [64m,64m+64) -> W slice 256 j-rows in REGISTERS
// (breg[2][8] = 64 VGPR/wave). h hi/lo packed in MFMA M-dim; per-step h exchange
// via agent-scope atomics + per-group flag counter (double-buffered by t parity).
template<bool WXF32>
__global__ __launch_bounds__(512, 2) void k_lstm4(const void* __restrict__ WxT,
        const unsigned short* __restrict__ whh_f, float* __restrict__ out,
        unsigned int* __restrict__ hbuf, int* __restrict__ flags){
  __shared__ __align__(16) char smem[8192 + 8448];
  char* HS = smem;                    // A-layout h: [row16][k256 bf16], XOR (row&7)<<3
  float* GS = (float*)(smem + 8192);  // gate stage: [batch][col][gate], stride 260/batch
  int tid = threadIdx.x, lane = tid & 63, wv = tid >> 6;
  int l15 = lane & 15, g = lane >> 4;
  int bid = blockIdx.x;
  int x = bid & 7, q = bid >> 3;          // same-XCD grouping: members differ by 8 in bid
  int y = q >> 2, m = q & 3;
  int grp = y * 8 + x;                    // [0,64)
  int b0 = grp * 8;
  int c0 = m * 64;
  int tb = tid >> 6, tc = tid & 63;       // gate-phase (batch, col_local)

  // ---- W slice into registers: wave w owns j_local [32w, 32w+32) (= [gate][col] order)
  U8 breg[2][8];
  #pragma unroll
  for (int nt = 0; nt < 2; ++nt){
    int jl = wv * 32 + nt * 16 + l15;
    int jg = (jl >> 6) * 256 + c0 + (jl & 63);
    #pragma unroll
    for (int kk = 0; kk < 8; ++kk)
      breg[nt][kk].i = *(const int4v*)((const char*)whh_f + (size_t)jg * 512 + kk * 64 + g * 16);
  }
  { int4v z = {0,0,0,0}; *(int4v*)(HS + tid * 16) = z; }   // h(=0) for t=0
  float cst = 0.f;
  __syncthreads();

  int swA = (l15 & 7) << 3;
  const char* hsrow = HS + l15 * 512;
  int keep = g >> 1;
  #pragma unroll 1
  for (int t = 0; t < 128; ++t){
    // ---- Wx for this step (4 coalesced scalars; L3-hot, hidden under MFMAs)
    float wx[4];
    {
      size_t ob = ((size_t)t * 512 + b0 + tb) * 1024 + c0 + tc;
      #pragma unroll
      for (int gate = 0; gate < 4; ++gate)
        wx[gate] = WXF32 ? ((const float*)WxT)[ob + gate * 256]
                         : bf2f(((const unsigned short*)WxT)[ob + gate * 256]);
    }
    // ---- matmul: acc[2] = h(hi/lo 16 rows) @ Wslice
    f32x4 zro = {0.f, 0.f, 0.f, 0.f};
    f32x4 acc[2] = {zro, zro};
    #pragma unroll
    for (int kk = 0; kk < 8; ++kk){
      U8 a;
      a.h[0] = *(const short4v*)(hsrow + ((kk * 64 + 8 * g) ^ swA));
      a.h[1] = *(const short4v*)(hsrow + ((kk * 64 + 32 + 8 * g) ^ swA));
      acc[0] = __builtin_amdgcn_mfma_f32_16x16x32_bf16(a.v, breg[0][kk].v, acc[0], 0, 0, 0);
      acc[1] = __builtin_amdgcn_mfma_f32_16x16x32_bf16(a.v, breg[1][kk].v, acc[1], 0, 0, 0);
    }
    // ---- fold hi+lo (keep own nt, send the other; partner g^2 holds the other rows)
    #pragma unroll
    for (int r = 0; r < 4; ++r){
      float v0 = acc[0][r], v1 = acc[1][r];
      float kv = keep ? v1 : v0;
      float sv = keep ? v0 : v1;
      float val = kv + __shfl_xor(sv, 32);
      int jl = wv * 32 + keep * 16 + l15;
      int batch = (g & 1) * 4 + r;
      GS[batch * 260 + (jl & 63) * 4 + (jl >> 6)] = val;
    }
    __syncthreads();
    // ---- gate phase: thread owns (tb, tc); 4 gates as one b128
    f32x4 gv = *(const f32x4*)(GS + tb * 260 + tc * 4);
    float gi = sigm(gv[0] + wx[0]);
    float gf = sigm(gv[1] + wx[1]);
    float gg = tanhf_(gv[2] + wx[2]);
    float go = sigm(gv[3] + wx[3]);
    float c = gf * cst + gi * gg;
    cst = c;
    float h = go * tanhf_(c);
    out[((size_t)(b0 + tb) * 128 + t) * 256 + c0 + tc] = h;
    if (t < 127){
      unsigned short hhi = f2bf(h);
      unsigned short hlo = f2bf(h - bf2f(hhi));
      unsigned int pk = (unsigned int)hhi | ((unsigned int)hlo << 16);
      unsigned int* hb = hbuf + ((size_t)grp * 2 + (t & 1)) * 2048;
      __hip_atomic_store(hb + tb * 256 + c0 + tc, pk, __ATOMIC_RELAXED, __HIP_MEMORY_SCOPE_AGENT);
      __syncthreads();                    // vmcnt drained -> all 512 stores agent-visible
      if (tid == 0){
        __hip_atomic_fetch_add(&flags[grp], 1, __ATOMIC_RELEASE, __HIP_MEMORY_SCOPE_AGENT);
        int target = 4 * (t + 1);
        while (__hip_atomic_load(&flags[grp], __ATOMIC_ACQUIRE, __HIP_MEMORY_SCOPE_AGENT) < target)
          __builtin_amdgcn_s_sleep(1);
      }
      __syncthreads();
      // ---- reload all 256 cols of h into HS (agent atomic u64 loads bypass L1)
      {
        int bb = tid >> 6, cg = tid & 63;          // 4 cols per thread
        const unsigned long long* sp =
            (const unsigned long long*)(hb + bb * 256 + cg * 4);
        unsigned long long w0 = __hip_atomic_load(sp,     __ATOMIC_RELAXED, __HIP_MEMORY_SCOPE_AGENT);
        unsigned long long w1 = __hip_atomic_load(sp + 1, __ATOMIC_RELAXED, __HIP_MEMORY_SCOPE_AGENT);
        unsigned int u0 = (unsigned int)w0, u1 = (unsigned int)(w0 >> 32);
        unsigned int u2 = (unsigned int)w1, u3 = (unsigned int)(w1 >> 32);
        short4v hiv = { (short)(u0 & 0xffff), (short)(u1 & 0xffff),
                        (short)(u2 & 0xffff), (short)(u3 & 0xffff) };
        short4v lov = { (short)(u0 >> 16), (short)(u1 >> 16),
                        (short)(u2 >> 16), (short)(u3 >> 16) };
        int sw = (bb & 7) << 3;
        int cb = (cg * 8) ^ sw;
        *(short4v*)(HS + bb * 512 + cb) = hiv;
        *(short4v*)(HS + (bb + 8) * 512 + cb) = lov;
      }
      __syncthreads();
    }
  }
}

// ---------------------------------------------------------------------------
extern "C" void kernel_launch(void* const* d_in, const int* in_sizes, int n_in,
                              void* d_out, int out_size, void* d_ws, size_t ws_size,
                              hipStream_t stream){
  (void)in_sizes; (void)n_in; (void)out_size;
  const float* X   = (const float*)d_in[0];
  const float* Wq  = (const float*)d_in[1];
  const float* Wk  = (const float*)d_in[2];
  const float* Wv  = (const float*)d_in[3];
  const float* Wih = (const float*)d_in[4];
  const float* Whh = (const float*)d_in[5];
  const float* bih = (const float*)d_in[6];
  const float* bhh = (const float*)d_in[7];
  float* out = (float*)d_out;
  char* ws = (char*)d_ws;

  const size_t SZ  = 33554432ULL;        // one (B,N,T) bf16 buffer
  const size_t WXF = 268435456ULL;       // Wx f32 (T,B,4H)
  const size_t WTS = 2200000ULL;         // casted weights + bias + hbuf + flags
  bool wxf32 = ws_size >= WXF + SZ + WTS;
  size_t wxb = wxf32 ? WXF : WXF / 2;

  unsigned short* p_xp = (unsigned short*)ws;
  unsigned short* p_q  = (unsigned short*)(ws + SZ);
  unsigned short* p_k  = (unsigned short*)(ws + 2 * SZ);
  unsigned short* p_vt = (unsigned short*)(ws + 3 * SZ);
  void* p_wx = (void*)ws;
  char* p = ws + wxb;
  unsigned short* p_xa  = (unsigned short*)p; p += SZ;
  unsigned short* p_wqb = (unsigned short*)p; p += 32768;
  unsigned short* p_wkb = (unsigned short*)p; p += 32768;
  unsigned short* p_wvb = (unsigned short*)p; p += 32768;
  unsigned short* p_wihb= (unsigned short*)p; p += 524288;
  unsigned short* p_whhf= (unsigned short*)p; p += 524288;
  float* p_bias = (float*)p; p += 4096;
  unsigned int* p_hbuf = (unsigned int*)p; p += 1048576;
  int* p_flags = (int*)p;

  k_prep<<<1024, 256, 0, stream>>>(Wq, Wk, Wv, Wih, bih, bhh,
                                   p_wqb, p_wkb, p_wvb, p_wihb, p_bias, p_flags);
  k_prep2<<<32, 256, 0, stream>>>(Whh, p_whhf);
  k_xpose<<<dim3(4, 512), 256, 0, stream>>>(X, p_xp);
  k_qkv<<<dim3(1024, 3), 256, 0, stream>>>(p_xp, p_wqb, p_wkb, p_wvb, p_q, p_k, p_vt);
  k_attn<<<dim3(4, 512), 256, 0, stream>>>(p_q, p_k, p_vt, p_xa);
  if (wxf32){
    k_wx<true><<<dim3(512, 8), 256, 0, stream>>>(p_xa, p_wihb, p_bias, p_wx);
    k_lstm4<true><<<256, 512, 0, stream>>>(p_wx, p_whhf, out, p_hbuf, p_flags);
  } else {
    k_wx<false><<<dim3(512, 8), 256, 0, stream>>>(p_xa, p_wihb, p_bias, p_wx);
    k_lstm4<false><<<256, 512, 0, stream>>>(p_wx, p_whhf, out, p_hbuf, p_flags);
  }
}

// Round 6
// 613.609 us; speedup vs baseline: 4.3476x; 2.6709x over previous
//
#include <hip/hip_runtime.h>
#include <hip/hip_bf16.h>
#include <stdint.h>

// Encoder: X->(transpose)->QKV GEMMs -> attention(softmax) -> Wx GEMM -> 128-step LSTM
// B=512 T=128 N=256 H=256, all inputs f32, output f32 (B,T,H).
// Round 6: k_lstm5 — R5 structure, but sync rebuilt with RELAXED system-scope atomics
// (R5's acquire/release emitted buffer_inv / buffer_wbl2 = whole-L2 invalidate/writeback
// per poll/step: 27k cy/step). Ordering via __syncthreads vmcnt-drain. Per-member flag
// slots, parallel poll, Wx prefetch, conflict-free GS layout.

#define DI __device__ __forceinline__

typedef __attribute__((ext_vector_type(8))) short bf16x8;   // 8 bf16 = 4 VGPR (MFMA A/B frag)
typedef __attribute__((ext_vector_type(4))) short short4v;  // 8B
typedef __attribute__((ext_vector_type(4))) float f32x4;    // MFMA C/D frag
typedef __attribute__((ext_vector_type(4))) int int4v;      // 16B

union U8 { bf16x8 v; short4v h[2]; int4v i; };

DI unsigned short f2bf(float x){
  union { float f; unsigned u; } v; v.f = x;
  unsigned r = v.u + 0x7fffu + ((v.u >> 16) & 1u);
  return (unsigned short)(r >> 16);
}
DI float bf2f(unsigned short x){
  union { unsigned u; float f; } v; v.u = ((unsigned)x) << 16; return v.f;
}
DI float rcp_(float x){ return __builtin_amdgcn_rcpf(x); }
DI float sigm(float x){ return rcp_(1.0f + __expf(-x)); }
DI float tanhf_(float x){ return 1.0f - 2.0f * rcp_(1.0f + __expf(2.0f * x)); }

#define BB 512
#define TT 128
#define NN 256
#define HH 256

// ---------------------------------------------------------------------------
// K0: cast weights to bf16, fuse biases, zero the per-member sync flags
__global__ void k_prep(const float* __restrict__ Wq, const float* __restrict__ Wk,
                       const float* __restrict__ Wv, const float* __restrict__ Wih,
                       const float* __restrict__ bih, const float* __restrict__ bhh,
                       unsigned short* __restrict__ wqb, unsigned short* __restrict__ wkb,
                       unsigned short* __restrict__ wvb, unsigned short* __restrict__ wihb,
                       float* __restrict__ bias, int* __restrict__ flags){
  int i = blockIdx.x * 256 + threadIdx.x;
  if (i < 16384){ wqb[i] = f2bf(Wq[i]); wkb[i] = f2bf(Wk[i]); wvb[i] = f2bf(Wv[i]); }
  if (i < 262144){ wihb[i] = f2bf(Wih[i]); }
  if (i < 1024){ bias[i] = bih[i] + bhh[i]; }
  if (i < 256){ flags[i] = 0; }
}

// K0b: W_hh -> fragment-major bf16: frag (j, kk, g) holds
// W[j][kk*32+4g+{0..3}] , W[j][kk*32+16+4g+{0..3}].  Byte = j*512 + kk*64 + g*16.
__global__ void k_prep2(const float* __restrict__ Whh, unsigned short* __restrict__ whh_f){
  int idx = blockIdx.x * 256 + threadIdx.x;   // 8192 = 1024 j x 8 kk
  int j = idx >> 3, kk = idx & 7;
  const float* src = Whh + j * 256 + kk * 32;
  unsigned short o[32];
  #pragma unroll
  for (int g = 0; g < 4; ++g)
    #pragma unroll
    for (int e = 0; e < 4; ++e){
      o[g * 8 + e]     = f2bf(src[4 * g + e]);
      o[g * 8 + 4 + e] = f2bf(src[16 + 4 * g + e]);
    }
  int4v* dst = (int4v*)((char*)whh_f + j * 512 + kk * 64);
  #pragma unroll
  for (int q = 0; q < 4; ++q) dst[q] = *(int4v*)(o + q * 8);
}

// ---------------------------------------------------------------------------
// K1: X (B,T,N) f32 -> Xp (B,N,T) bf16   (tile transpose through LDS)
__global__ __launch_bounds__(256) void k_xpose(const float* __restrict__ X,
                                               unsigned short* __restrict__ Xp){
  __shared__ float tile[128][65];
  int b = blockIdx.y, n0 = blockIdx.x * 64;
  int tid = threadIdx.x;
  int nloc = tid & 63, t0 = tid >> 6;
  const float* src = X + (size_t)b * TT * NN + n0 + nloc;
  #pragma unroll
  for (int r = 0; r < 32; ++r){
    int t = r * 4 + t0;
    tile[t][nloc] = src[(size_t)t * NN];
  }
  __syncthreads();
  int tl = tid & 127, nr0 = tid >> 7;
  unsigned short* dst = Xp + ((size_t)b * NN + n0) * TT + tl;
  #pragma unroll
  for (int r = 0; r < 32; ++r){
    int n = r * 2 + nr0;
    dst[(size_t)n * TT] = f2bf(tile[tl][n]);
  }
}

// ---------------------------------------------------------------------------
// K2: Q/K/V = Xp @ W^T per batch.  M=131072 rows, N=128, K=128.  blockIdx.y = mode.
__global__ __launch_bounds__(256) void k_qkv(const unsigned short* __restrict__ Xp,
      const unsigned short* __restrict__ Wqb, const unsigned short* __restrict__ Wkb,
      const unsigned short* __restrict__ Wvb,
      unsigned short* __restrict__ Qo, unsigned short* __restrict__ Ko,
      unsigned short* __restrict__ Vo){
  __shared__ __align__(16) char smem[32768 + 8192];
  unsigned short* Bs = (unsigned short*)smem;
  char* As = smem + 32768;
  char* Os = smem;
  int mode = blockIdx.y;
  const unsigned short* W = (mode == 0) ? Wqb : ((mode == 1) ? Wkb : Wvb);
  int m0 = blockIdx.x * 128;
  int tid = threadIdx.x;

  #pragma unroll
  for (int it = 0; it < 16; ++it){
    int c = it * 256 + tid;
    int j = c >> 5;
    int kc = (c & 31) << 2;
    short4v v = *(const short4v*)(W + j * 128 + kc);
    *(short4v*)((char*)Bs + j * 256 + ((kc * 2) ^ ((j & 7) << 4))) = v;
  }

  int lane = tid & 63, wv = tid >> 6;
  int wr = wv >> 1, wc = wv & 1;
  int l15 = lane & 15, g = lane >> 4;
  f32x4 zro = {0.f, 0.f, 0.f, 0.f};
  f32x4 acc[4][4];
  #pragma unroll
  for (int a = 0; a < 4; ++a)
    #pragma unroll
    for (int bq = 0; bq < 4; ++bq) acc[a][bq] = zro;

  int arow = tid >> 1, ahalf = (tid & 1) * 16;
  const unsigned short* Ap = Xp + (size_t)(m0 + arow) * 128;

  for (int ks = 0; ks < 4; ++ks){
    __syncthreads();
    {
      const unsigned short* s = Ap + ks * 32 + ahalf;
      char* base = As + arow * 64;
      int kb = ahalf * 2;
      int sw = (arow & 7) << 3;
      *(short4v*)(base + ((kb     ) ^ sw)) = *(const short4v*)(s);
      *(short4v*)(base + ((kb +  8) ^ sw)) = *(const short4v*)(s + 4);
      *(short4v*)(base + ((kb + 16) ^ sw)) = *(const short4v*)(s + 8);
      *(short4v*)(base + ((kb + 24) ^ sw)) = *(const short4v*)(s + 12);
    }
    __syncthreads();
    U8 af[4];
    #pragma unroll
    for (int mt = 0; mt < 4; ++mt){
      int ar = wr * 64 + mt * 16 + l15;
      const char* ab = As + ar * 64;
      int sw = (ar & 7) << 3;
      af[mt].h[0] = *(const short4v*)(ab + ((8 * g) ^ sw));
      af[mt].h[1] = *(const short4v*)(ab + ((8 * g + 32) ^ sw));
    }
    #pragma unroll
    for (int nt = 0; nt < 4; ++nt){
      int jr = wc * 64 + nt * 16 + l15;
      const char* bb = (const char*)Bs + jr * 256;
      int kb = ks * 64 + 8 * g, sw = (jr & 7) << 4;
      U8 bf;
      bf.h[0] = *(const short4v*)(bb + (kb ^ sw));
      bf.h[1] = *(const short4v*)(bb + ((kb + 32) ^ sw));
      #pragma unroll
      for (int mt = 0; mt < 4; ++mt)
        acc[mt][nt] = __builtin_amdgcn_mfma_f32_16x16x32_bf16(af[mt].v, bf.v, acc[mt][nt], 0, 0, 0);
    }
  }
  __syncthreads();
  float scale = (mode == 0) ? 0.0625f : 1.0f;
  #pragma unroll
  for (int mt = 0; mt < 4; ++mt)
    #pragma unroll
    for (int nt = 0; nt < 4; ++nt)
      #pragma unroll
      for (int r = 0; r < 4; ++r){
        int row = wr * 64 + mt * 16 + g * 4 + r;
        int col = wc * 64 + nt * 16 + l15;
        unsigned short hv = f2bf(acc[mt][nt][r] * scale);
        int addr = (mode == 2) ? (col * 256 + ((row * 2) ^ ((col & 7) << 4)))
                               : (row * 256 + ((col * 2) ^ ((row & 7) << 4)));
        *(unsigned short*)(Os + addr) = hv;
      }
  __syncthreads();
  int orow = tid >> 1, oseg = tid & 1;
  const char* srcrow = Os + orow * 256;
  unsigned short* dst;
  if (mode == 2){
    int bq = m0 >> 8, ibase = m0 & 255;
    dst = Vo + ((size_t)bq * 128 + orow) * 256 + ibase + oseg * 64;
  } else {
    dst = ((mode == 0) ? Qo : Ko) + (size_t)(m0 + orow) * 128 + oseg * 64;
  }
  #pragma unroll
  for (int c = 0; c < 8; ++c){
    int kb = oseg * 128 + c * 16;
    *(int4v*)((char*)dst + c * 16) = *(const int4v*)(srcrow + (kb ^ ((orow & 7) << 4)));
  }
}

// ---------------------------------------------------------------------------
// K3: fused attention per (b, 64-row i-tile). S=QK^T, softmax, Xa^T = V^T P^T.
__global__ __launch_bounds__(256) void k_attn(const unsigned short* __restrict__ Q,
        const unsigned short* __restrict__ K, const unsigned short* __restrict__ Vt,
        unsigned short* __restrict__ Xa){
  __shared__ __align__(16) char smem[16384 + 65536 + 32768 + 256];
  char* Qs = smem;
  char* Ks = smem + 16384;
  char* Ps = smem + 16384 + 65536;
  float* rden = (float*)(smem + 16384 + 65536 + 32768);
  int b = blockIdx.y, i0 = blockIdx.x * 64;
  int tid = threadIdx.x, lane = tid & 63, wv = tid >> 6;
  int l15 = lane & 15, g = lane >> 4;

  {
    int row = tid >> 2, q = tid & 3;
    const char* src = (const char*)(Q + ((size_t)b * 256 + i0 + row) * 128) + q * 64;
    char* dstr = Qs + row * 256;
    int sw = (row & 7) << 4;
    #pragma unroll
    for (int c = 0; c < 4; ++c){
      int kb = q * 64 + c * 16;
      *(int4v*)(dstr + (kb ^ sw)) = *(const int4v*)(src + c * 16);
    }
  }
  {
    const char* src = (const char*)(K + ((size_t)b * 256 + tid) * 128);
    char* dstr = Ks + tid * 256;
    int sw = (tid & 7) << 4;
    #pragma unroll
    for (int c = 0; c < 16; ++c)
      *(int4v*)(dstr + ((c * 16) ^ sw)) = *(const int4v*)(src + c * 16);
  }
  __syncthreads();

  f32x4 zro = {0.f, 0.f, 0.f, 0.f};
  f32x4 acc[16];
  #pragma unroll
  for (int nt = 0; nt < 16; ++nt) acc[nt] = zro;
  #pragma unroll
  for (int kk = 0; kk < 4; ++kk){
    int ar = wv * 16 + l15;
    const char* ab = Qs + ar * 256;
    int kb = kk * 64 + 8 * g, swa = (ar & 7) << 4;
    U8 a;
    a.h[0] = *(const short4v*)(ab + (kb ^ swa));
    a.h[1] = *(const short4v*)(ab + ((kb + 32) ^ swa));
    #pragma unroll
    for (int nt = 0; nt < 16; ++nt){
      int jr = nt * 16 + l15;
      const char* bb = Ks + jr * 256;
      int swb = (jr & 7) << 4;
      U8 bf;
      bf.h[0] = *(const short4v*)(bb + (kb ^ swb));
      bf.h[1] = *(const short4v*)(bb + ((kb + 32) ^ swb));
      acc[nt] = __builtin_amdgcn_mfma_f32_16x16x32_bf16(a.v, bf.v, acc[nt], 0, 0, 0);
    }
  }
  float mx[4], sm[4];
  #pragma unroll
  for (int r = 0; r < 4; ++r){
    float m = acc[0][r];
    #pragma unroll
    for (int nt = 1; nt < 16; ++nt) m = fmaxf(m, acc[nt][r]);
    #pragma unroll
    for (int s = 1; s < 16; s <<= 1) m = fmaxf(m, __shfl_xor(m, s));
    mx[r] = m;
  }
  #pragma unroll
  for (int r = 0; r < 4; ++r){
    float s = 0.f;
    #pragma unroll
    for (int nt = 0; nt < 16; ++nt){
      float p = __expf(acc[nt][r] - mx[r]);
      acc[nt][r] = p; s += p;
    }
    #pragma unroll
    for (int sd = 1; sd < 16; sd <<= 1) s += __shfl_xor(s, sd);
    sm[r] = s;
  }
  #pragma unroll
  for (int nt = 0; nt < 16; ++nt)
    #pragma unroll
    for (int r = 0; r < 4; ++r){
      int ir = wv * 16 + g * 4 + r;
      *(unsigned short*)(Ps + ir * 512 + ((nt * 16 + l15) * 2 ^ ((ir & 7) << 4))) = f2bf(acc[nt][r]);
    }
  #pragma unroll
  for (int r = 0; r < 4; ++r)
    if (l15 == r) rden[wv * 16 + g * 4 + r] = rcp_(sm[r]);
  __syncthreads();
  {
    int row = tid >> 1, half = tid & 1;
    const char* src = (const char*)(Vt + ((size_t)b * 128 + row) * 256) + half * 256;
    char* dstr = Ks + row * 512;
    int sw = (row & 7) << 4;
    #pragma unroll
    for (int c = 0; c < 16; ++c){
      int jb = half * 256 + c * 16;
      *(int4v*)(dstr + (jb ^ sw)) = *(const int4v*)(src + c * 16);
    }
  }
  __syncthreads();

  f32x4 acc2[2][4];
  #pragma unroll
  for (int mt = 0; mt < 2; ++mt)
    #pragma unroll
    for (int nt = 0; nt < 4; ++nt) acc2[mt][nt] = zro;
  #pragma unroll
  for (int kk = 0; kk < 8; ++kk){
    int kb = kk * 64 + 8 * g;
    U8 bfr[4];
    #pragma unroll
    for (int nt = 0; nt < 4; ++nt){
      int ir = nt * 16 + l15;
      const char* pb = Ps + ir * 512;
      int sw = (ir & 7) << 4;
      bfr[nt].h[0] = *(const short4v*)(pb + (kb ^ sw));
      bfr[nt].h[1] = *(const short4v*)(pb + ((kb + 32) ^ sw));
    }
    #pragma unroll
    for (int mt = 0; mt < 2; ++mt){
      int tr = wv * 32 + mt * 16 + l15;
      const char* ab = Ks + tr * 512;
      int sw = (tr & 7) << 4;
      U8 a;
      a.h[0] = *(const short4v*)(ab + (kb ^ sw));
      a.h[1] = *(const short4v*)(ab + ((kb + 32) ^ sw));
      #pragma unroll
      for (int nt = 0; nt < 4; ++nt)
        acc2[mt][nt] = __builtin_amdgcn_mfma_f32_16x16x32_bf16(a.v, bfr[nt].v, acc2[mt][nt], 0, 0, 0);
    }
  }
  #pragma unroll
  for (int nt = 0; nt < 4; ++nt){
    float rd = rden[nt * 16 + l15];
    #pragma unroll
    for (int mt = 0; mt < 2; ++mt)
      #pragma unroll
      for (int r = 0; r < 4; ++r){
        int t = wv * 32 + mt * 16 + g * 4 + r;
        int i = i0 + nt * 16 + l15;
        Xa[((size_t)b * 128 + t) * 256 + i] = f2bf(acc2[mt][nt][r] * rd);
      }
  }
}

// ---------------------------------------------------------------------------
// K4: Wx = Xa @ W_ih^T + bias, written time-major (T,B,4H).
template<bool WXF32>
__global__ __launch_bounds__(256) void k_wx(const unsigned short* __restrict__ Xa,
        const unsigned short* __restrict__ Wih, const float* __restrict__ bias,
        void* __restrict__ WxT){
  __shared__ __align__(16) char smem[65536 + 8192];
  char* Bsm = smem;
  char* As = smem + 65536;
  int bidx = blockIdx.x;
  int j0 = blockIdx.y * 128;
  int tid = threadIdx.x;
  {
    int row = tid >> 1, half = tid & 1;
    const char* src = (const char*)(Wih + (size_t)(j0 + row) * 256) + half * 256;
    char* dstr = Bsm + row * 512;
    int sw = (row & 7) << 4;
    #pragma unroll
    for (int c = 0; c < 16; ++c){
      int kb = half * 256 + c * 16;
      *(int4v*)(dstr + (kb ^ sw)) = *(const int4v*)(src + c * 16);
    }
  }
  int lane = tid & 63, wv = tid >> 6, wr = wv >> 1, wc = wv & 1;
  int l15 = lane & 15, g = lane >> 4;
  f32x4 zro = {0.f, 0.f, 0.f, 0.f};
  f32x4 acc[4][4];
  #pragma unroll
  for (int a = 0; a < 4; ++a)
    #pragma unroll
    for (int bq = 0; bq < 4; ++bq) acc[a][bq] = zro;
  int arow = tid >> 1, ahalf = (tid & 1) * 16;
  const unsigned short* Ap = Xa + (size_t)(bidx * 128 + arow) * 256;
  for (int ks = 0; ks < 8; ++ks){
    __syncthreads();
    {
      const unsigned short* s = Ap + ks * 32 + ahalf;
      char* base = As + arow * 64;
      int kb = ahalf * 2, sw = (arow & 7) << 3;
      *(short4v*)(base + ((kb     ) ^ sw)) = *(const short4v*)(s);
      *(short4v*)(base + ((kb +  8) ^ sw)) = *(const short4v*)(s + 4);
      *(short4v*)(base + ((kb + 16) ^ sw)) = *(const short4v*)(s + 8);
      *(short4v*)(base + ((kb + 24) ^ sw)) = *(const short4v*)(s + 12);
    }
    __syncthreads();
    U8 af[4];
    #pragma unroll
    for (int mt = 0; mt < 4; ++mt){
      int ar = wr * 64 + mt * 16 + l15;
      const char* ab = As + ar * 64;
      int sw = (ar & 7) << 3;
      af[mt].h[0] = *(const short4v*)(ab + ((8 * g) ^ sw));
      af[mt].h[1] = *(const short4v*)(ab + ((8 * g + 32) ^ sw));
    }
    #pragma unroll
    for (int nt = 0; nt < 4; ++nt){
      int jr = wc * 64 + nt * 16 + l15;
      const char* bb = Bsm + jr * 512;
      int kb = ks * 64 + 8 * g, sw = (jr & 7) << 4;
      U8 bf;
      bf.h[0] = *(const short4v*)(bb + (kb ^ sw));
      bf.h[1] = *(const short4v*)(bb + ((kb + 32) ^ sw));
      #pragma unroll
      for (int mt = 0; mt < 4; ++mt)
        acc[mt][nt] = __builtin_amdgcn_mfma_f32_16x16x32_bf16(af[mt].v, bf.v, acc[mt][nt], 0, 0, 0);
    }
  }
  #pragma unroll
  for (int nt = 0; nt < 4; ++nt){
    int j = j0 + wc * 64 + nt * 16 + l15;
    float bs = bias[j];
    #pragma unroll
    for (int mt = 0; mt < 4; ++mt)
      #pragma unroll
      for (int r = 0; r < 4; ++r){
        int t = wr * 64 + mt * 16 + g * 4 + r;
        float v = acc[mt][nt][r] + bs;
        size_t o = ((size_t)t * 512 + bidx) * 1024 + j;
        if (WXF32) ((float*)WxT)[o] = v;
        else       ((unsigned short*)WxT)[o] = f2bf(v);
      }
  }
}

// ---------------------------------------------------------------------------
// K5 v5: LSTM, group-sharded W (R5 layout), relaxed-atomic sync.
// 256 blocks x 512 thr; group of 4 blocks = 8 batches; member m owns cols [64m,64m+64).
// All atomics RELAXED + SYSTEM scope (no buffer_inv/wbl2). Ordering: __syncthreads
// drains vmcnt => h stores complete at the coherence point before the flag store.
template<bool WXF32>
__global__ __launch_bounds__(512, 2) void k_lstm5(const void* __restrict__ WxT,
        const unsigned short* __restrict__ whh_f, float* __restrict__ out,
        unsigned int* __restrict__ hbuf, int* __restrict__ flags){
  __shared__ __align__(16) char smem[8192 + 8448];
  char* HS = smem;                    // A-layout h: [row16][k256 bf16], XOR (row&7)<<3
  float* GS = (float*)(smem + 8192);  // gate stage: [batch][gate][col], stride 264/batch
  int tid = threadIdx.x, lane = tid & 63, wv = tid >> 6;
  int l15 = lane & 15, g = lane >> 4;
  int bid = blockIdx.x;
  int x = bid & 7, q = bid >> 3;          // same-XCD grouping heuristic (bid mod 8)
  int y = q >> 2, m = q & 3;
  int grp = y * 8 + x;                    // [0,64)
  int b0 = grp * 8;
  int c0 = m * 64;
  int tb = tid >> 6, tc = tid & 63;       // gate-phase (batch, col_local)

  // ---- W slice into registers: wave w owns j_local [32w, 32w+32)
  U8 breg[2][8];
  #pragma unroll
  for (int nt = 0; nt < 2; ++nt){
    int jl = wv * 32 + nt * 16 + l15;
    int jg = (jl >> 6) * 256 + c0 + (jl & 63);
    #pragma unroll
    for (int kk = 0; kk < 8; ++kk)
      breg[nt][kk].i = *(const int4v*)((const char*)whh_f + (size_t)jg * 512 + kk * 64 + g * 16);
  }
  { int4v z = {0,0,0,0}; *(int4v*)(HS + tid * 16) = z; }   // h(=0) for t=0
  float cst = 0.f;
  __syncthreads();

  // Wx for t=0
  float wx[4];
  {
    size_t ob = ((size_t)b0 + tb) * 1024 + c0 + tc;
    #pragma unroll
    for (int gate = 0; gate < 4; ++gate)
      wx[gate] = WXF32 ? ((const float*)WxT)[ob + gate * 256]
                       : bf2f(((const unsigned short*)WxT)[ob + gate * 256]);
  }

  int swA = (l15 & 7) << 3;
  const char* hsrow = HS + l15 * 512;
  int keep = g >> 1;
  #pragma unroll 1
  for (int t = 0; t < 128; ++t){
    // ---- matmul: acc[2] = h(hi/lo 16 rows) @ Wslice
    f32x4 zro = {0.f, 0.f, 0.f, 0.f};
    f32x4 acc[2] = {zro, zro};
    #pragma unroll
    for (int kk = 0; kk < 8; ++kk){
      U8 a;
      a.h[0] = *(const short4v*)(hsrow + ((kk * 64 + 8 * g) ^ swA));
      a.h[1] = *(const short4v*)(hsrow + ((kk * 64 + 32 + 8 * g) ^ swA));
      acc[0] = __builtin_amdgcn_mfma_f32_16x16x32_bf16(a.v, breg[0][kk].v, acc[0], 0, 0, 0);
      acc[1] = __builtin_amdgcn_mfma_f32_16x16x32_bf16(a.v, breg[1][kk].v, acc[1], 0, 0, 0);
    }
    // ---- fold hi+lo (keep own nt, send the other; partner g^2 holds the other rows)
    #pragma unroll
    for (int r = 0; r < 4; ++r){
      float v0 = acc[0][r], v1 = acc[1][r];
      float kv = keep ? v1 : v0;
      float sv = keep ? v0 : v1;
      float val = kv + __shfl_xor(sv, 32);
      int jl = wv * 32 + keep * 16 + l15;
      int batch = (g & 1) * 4 + r;
      GS[batch * 264 + (jl >> 6) * 66 + (jl & 63)] = val;   // conflict-free layout
    }
    __syncthreads();
    // ---- gate phase: thread owns (tb, tc); 4 conflict-free b32 reads
    float gv0 = GS[tb * 264 +   0 + tc];
    float gv1 = GS[tb * 264 +  66 + tc];
    float gv2 = GS[tb * 264 + 132 + tc];
    float gv3 = GS[tb * 264 + 198 + tc];
    // prefetch Wx(t+1) — latency hides under publish/poll
    float wxn[4] = {0.f, 0.f, 0.f, 0.f};
    if (t < 127){
      size_t ob = ((size_t)(t + 1) * 512 + b0 + tb) * 1024 + c0 + tc;
      #pragma unroll
      for (int gate = 0; gate < 4; ++gate)
        wxn[gate] = WXF32 ? ((const float*)WxT)[ob + gate * 256]
                          : bf2f(((const unsigned short*)WxT)[ob + gate * 256]);
    }
    float gi = sigm(gv0 + wx[0]);
    float gf = sigm(gv1 + wx[1]);
    float gg = tanhf_(gv2 + wx[2]);
    float go = sigm(gv3 + wx[3]);
    float c = gf * cst + gi * gg;
    cst = c;
    float h = go * tanhf_(c);
    out[((size_t)(b0 + tb) * 128 + t) * 256 + c0 + tc] = h;
    if (t < 127){
      unsigned short hhi = f2bf(h);
      unsigned short hlo = f2bf(h - bf2f(hhi));
      unsigned int pk = (unsigned int)hhi | ((unsigned int)hlo << 16);
      unsigned int* hb = hbuf + ((size_t)grp * 2 + (t & 1)) * 2048;
      __hip_atomic_store(hb + tb * 256 + c0 + tc, pk, __ATOMIC_RELAXED, __HIP_MEMORY_SCOPE_SYSTEM);
      __syncthreads();                    // vmcnt(0) drain: h stores complete at coherence pt
      if (wv == 0){
        if (lane == 0)
          __hip_atomic_store(&flags[grp * 4 + m], t + 1, __ATOMIC_RELAXED, __HIP_MEMORY_SCOPE_SYSTEM);
        if (lane >= 1 && lane <= 3){
          int pl = lane - 1;
          int pslot = pl + (pl >= m ? 1 : 0);
          while (__hip_atomic_load(&flags[grp * 4 + pslot], __ATOMIC_RELAXED,
                                   __HIP_MEMORY_SCOPE_SYSTEM) <= t){}
        }
      }
      __syncthreads();
      // ---- reload all 256 cols of h into HS (relaxed system atomic u64 loads)
      {
        int bb = tid >> 6, cg = tid & 63;          // 4 cols per thread
        const unsigned long long* sp =
            (const unsigned long long*)(hb + bb * 256 + cg * 4);
        unsigned long long w0 = __hip_atomic_load(sp,     __ATOMIC_RELAXED, __HIP_MEMORY_SCOPE_SYSTEM);
        unsigned long long w1 = __hip_atomic_load(sp + 1, __ATOMIC_RELAXED, __HIP_MEMORY_SCOPE_SYSTEM);
        unsigned int u0 = (unsigned int)w0, u1 = (unsigned int)(w0 >> 32);
        unsigned int u2 = (unsigned int)w1, u3 = (unsigned int)(w1 >> 32);
        short4v hiv = { (short)(u0 & 0xffff), (short)(u1 & 0xffff),
                        (short)(u2 & 0xffff), (short)(u3 & 0xffff) };
        short4v lov = { (short)(u0 >> 16), (short)(u1 >> 16),
                        (short)(u2 >> 16), (short)(u3 >> 16) };
        int sw = (bb & 7) << 3;
        int cb = (cg * 8) ^ sw;
        *(short4v*)(HS + bb * 512 + cb) = hiv;
        *(short4v*)(HS + (bb + 8) * 512 + cb) = lov;
      }
      __syncthreads();
      wx[0] = wxn[0]; wx[1] = wxn[1]; wx[2] = wxn[2]; wx[3] = wxn[3];
    }
  }
}

// ---------------------------------------------------------------------------
extern "C" void kernel_launch(void* const* d_in, const int* in_sizes, int n_in,
                              void* d_out, int out_size, void* d_ws, size_t ws_size,
                              hipStream_t stream){
  (void)in_sizes; (void)n_in; (void)out_size;
  const float* X   = (const float*)d_in[0];
  const float* Wq  = (const float*)d_in[1];
  const float* Wk  = (const float*)d_in[2];
  const float* Wv  = (const float*)d_in[3];
  const float* Wih = (const float*)d_in[4];
  const float* Whh = (const float*)d_in[5];
  const float* bih = (const float*)d_in[6];
  const float* bhh = (const float*)d_in[7];
  float* out = (float*)d_out;
  char* ws = (char*)d_ws;

  const size_t SZ  = 33554432ULL;        // one (B,N,T) bf16 buffer
  const size_t WXF = 268435456ULL;       // Wx f32 (T,B,4H)
  const size_t WTS = 2200000ULL;         // casted weights + bias + hbuf + flags
  bool wxf32 = ws_size >= WXF + SZ + WTS;
  size_t wxb = wxf32 ? WXF : WXF / 2;

  unsigned short* p_xp = (unsigned short*)ws;
  unsigned short* p_q  = (unsigned short*)(ws + SZ);
  unsigned short* p_k  = (unsigned short*)(ws + 2 * SZ);
  unsigned short* p_vt = (unsigned short*)(ws + 3 * SZ);
  void* p_wx = (void*)ws;
  char* p = ws + wxb;
  unsigned short* p_xa  = (unsigned short*)p; p += SZ;
  unsigned short* p_wqb = (unsigned short*)p; p += 32768;
  unsigned short* p_wkb = (unsigned short*)p; p += 32768;
  unsigned short* p_wvb = (unsigned short*)p; p += 32768;
  unsigned short* p_wihb= (unsigned short*)p; p += 524288;
  unsigned short* p_whhf= (unsigned short*)p; p += 524288;
  float* p_bias = (float*)p; p += 4096;
  unsigned int* p_hbuf = (unsigned int*)p; p += 1048576;
  int* p_flags = (int*)p;

  k_prep<<<1024, 256, 0, stream>>>(Wq, Wk, Wv, Wih, bih, bhh,
                                   p_wqb, p_wkb, p_wvb, p_wihb, p_bias, p_flags);
  k_prep2<<<32, 256, 0, stream>>>(Whh, p_whhf);
  k_xpose<<<dim3(4, 512), 256, 0, stream>>>(X, p_xp);
  k_qkv<<<dim3(1024, 3), 256, 0, stream>>>(p_xp, p_wqb, p_wkb, p_wvb, p_q, p_k, p_vt);
  k_attn<<<dim3(4, 512), 256, 0, stream>>>(p_q, p_k, p_vt, p_xa);
  if (wxf32){
    k_wx<true><<<dim3(512, 8), 256, 0, stream>>>(p_xa, p_wihb, p_bias, p_wx);
    k_lstm5<true><<<256, 512, 0, stream>>>(p_wx, p_whhf, out, p_hbuf, p_flags);
  } else {
    k_wx<false><<<dim3(512, 8), 256, 0, stream>>>(p_xa, p_wihb, p_bias, p_wx);
    k_lstm5<false><<<256, 512, 0, stream>>>(p_wx, p_whhf, out, p_hbuf, p_flags);
  }
}